// Round 10
// baseline (222.168 us; speedup 1.0000x reference)
//
#include <hip/hip_runtime.h>

#define NN 50000
#define NE 800000
#define DEGCAP 64                              // max in-degree (Poisson(16): P(>64)~1e-15)

// K1 geometry: scatter blocks FIRST (XCD classes + overlap with cvt)
#define NXCD 8
#define NPS ((NN + NXCD - 1) / NXCD)           // 6250 nodes per XCD slot
#define SEPB 4096                              // edges per chunk
#define NCHUNK ((NE + SEPB - 1) / SEPB)        // 196
#define SCAT_BLKS (NCHUNK * NXCD)              // 1568
#define CVT_BLKS 6250                          // NN*128/4/256 exactly
#define PREP_BLKS 32
#define K1_GRID (SCAT_BLKS + CVT_BLKS + PREP_BLKS + 1)

typedef short short8 __attribute__((ext_vector_type(8)));
typedef short short4v __attribute__((ext_vector_type(4)));
typedef float f32x4 __attribute__((ext_vector_type(4)));
typedef _Float16 half8v __attribute__((ext_vector_type(8)));

__device__ inline unsigned short f16_bits(float f) {
    _Float16 h = (_Float16)f;                  // v_cvt_f16_f32, RNE
    return __builtin_bit_cast(unsigned short, h);
}

// ---- K1: scatter (XCD-partitioned, u16) | cvt x->fp16 | wprep | zero-rows --
// r9 post-mortem: cooperative launch no-ops under graph capture -> fuse only
// where no global sync is needed. Scatter needs deg=0 (hipMemsetAsync before);
// scatter/cvt/wprep are mutually independent -> one launch, scatter blocks
// first so the L2-atomic-bound scatter overlaps the HBM-bound cvt.
__global__ __launch_bounds__(256) void k1_kernel(const float* __restrict__ x,
                                                 unsigned short* __restrict__ xb,
                                                 const float* __restrict__ W0,
                                                 const float* __restrict__ W1,
                                                 const float* __restrict__ W2,
                                                 const float* __restrict__ W3,
                                                 short* __restrict__ wf,
                                                 int* __restrict__ deg,
                                                 unsigned short* __restrict__ col,
                                                 const int* __restrict__ src,
                                                 const int* __restrict__ dst,
                                                 unsigned short* __restrict__ h1b) {
    int b = blockIdx.x;
    if (b < SCAT_BLKS) {                      // edge scatter (r8-validated)
        int slot8 = b & 7;                    // stable XCD class (round-robin dispatch)
        int chunk = b >> 3;
        int lo = slot8 * NPS, hi = lo + NPS;
        int base = chunk * SEPB;
        int end = base + SEPB;
        if (end > NE) end = NE;
        for (int i = base + (int)threadIdx.x; i < end; i += 256) {
            int d = dst[i];
            if (d >= lo && d < hi) {
                int s = src[i];
                int sl = atomicAdd(&deg[d], 1);
                col[((size_t)d << 6) + sl] = (unsigned short)s;
            }
        }
    } else if (b < SCAT_BLKS + CVT_BLKS) {    // x -> fp16 (one float4/thread, exact)
        int i = (b - SCAT_BLKS) * 256 + threadIdx.x;
        float4 v = ((const float4*)x)[i];
        short4v r;
        r[0] = (short)f16_bits(v.x);
        r[1] = (short)f16_bits(v.y);
        r[2] = (short)f16_bits(v.z);
        r[3] = (short)f16_bits(v.w);
        ((short4v*)xb)[i] = r;
    } else if (b < SCAT_BLKS + CVT_BLKS + PREP_BLKS) {  // weight fragment reorder
        int t = (b - SCAT_BLKS - CVT_BLKS) * 256 + threadIdx.x;   // 0..8191
        int mat = t >> 11;
        const float* W = (mat == 0) ? W0 : (mat == 1) ? W1 : (mat == 2) ? W2 : W3;
        short* out = wf + (size_t)mat * 16384;
        int r = t & 2047;
        int nt = r >> 8;
        int kc = (r >> 6) & 3;
        int lane = r & 63;
        int n = nt * 16 + (lane & 15);
        int kbase = kc * 32 + ((lane >> 4) << 3);
        short8 vh;
#pragma unroll
        for (int j = 0; j < 8; ++j) {
            float w = W[(size_t)(kbase + j) * 128 + n];
            vh[j] = (short)f16_bits(w);
        }
        size_t o = ((size_t)((nt * 4 + kc) * 64 + lane)) * 8;
        *(short8*)(out + o) = vh;
    } else {                                  // zero feature rows at index NN
        int t = threadIdx.x;
        short8 z = {0, 0, 0, 0, 0, 0, 0, 0};
        if (t < 16) *(short8*)(xb + ((size_t)NN << 7) + (t << 3)) = z;
        else if (t < 32) *(short8*)(h1b + ((size_t)NN << 7) + ((t - 16) << 3)) = z;
    }
}

// ------- fused SAGE layer: gather+mean -> dual fp16 MFMA (+opt. fused FC) ----
// r4-validated structure (57.6us, absmax 0.00195), ported to slotted u16 col:
// lane (quad,m16) gathers feats kc*32+quad*8..+7 of row m16 directly in the
// MFMA A-fragment layout (no cross-lane reduce, no aggb round-trip). 4-edge
// batches x 4 kc = 16x16B loads in flight/lane; fp16 pairwise tree (r6-
// validated) then fp32 accumulate.
__global__ __launch_bounds__(256) void fused_sage(const unsigned short* __restrict__ hb,
                                                  const unsigned short* __restrict__ col,
                                                  const int* __restrict__ deg,
                                                  const short* __restrict__ Wf0,
                                                  const short* __restrict__ Wf1,
                                                  const float* __restrict__ bias,
                                                  unsigned short* __restrict__ outb,
                                                  const float* __restrict__ Wfc,
                                                  const float* __restrict__ bfc,
                                                  float* __restrict__ fcout,
                                                  int relu) {
    int lane = threadIdx.x & 63;
    int wave = threadIdx.x >> 6;
    int quad = lane >> 4, m16 = lane & 15;
    int row_base = blockIdx.x * 64 + wave * 16;
    int arow = row_base + m16;
    if (arow > NN - 1) arow = NN - 1;          // clamp (dup gather harmless)

    int dg = deg[arow];
    const unsigned short* cp = col + ((size_t)arow << 6);
    const unsigned short* tq = hb + (quad << 3);   // + c*128 + kc*32

    float accg[4][8];
#pragma unroll
    for (int kc = 0; kc < 4; ++kc)
#pragma unroll
        for (int j = 0; j < 8; ++j) accg[kc][j] = 0.f;

    int e = 0;
    for (; e + 4 <= dg; e += 4) {                  // 4-edge batch: 16 loads in flight
        int c0 = cp[e], c1 = cp[e + 1], c2 = cp[e + 2], c3 = cp[e + 3];
        const unsigned short* r0 = tq + ((size_t)c0 << 7);
        const unsigned short* r1 = tq + ((size_t)c1 << 7);
        const unsigned short* r2 = tq + ((size_t)c2 << 7);
        const unsigned short* r3 = tq + ((size_t)c3 << 7);
#pragma unroll
        for (int kc = 0; kc < 4; ++kc) {
            half8v v0 = *(const half8v*)(r0 + kc * 32);
            half8v v1 = *(const half8v*)(r1 + kc * 32);
            half8v v2 = *(const half8v*)(r2 + kc * 32);
            half8v v3 = *(const half8v*)(r3 + kc * 32);
            half8v s = (v0 + v1) + (v2 + v3);      // fp16 tree (r6-validated)
#pragma unroll
            for (int q = 0; q < 8; ++q) accg[kc][q] += (float)s[q];
        }
    }
    for (; e < dg; ++e) {                          // scalar remainder
        const unsigned short* r0 = tq + ((size_t)cp[e] << 7);
#pragma unroll
        for (int kc = 0; kc < 4; ++kc) {
            half8v v0 = *(const half8v*)(r0 + kc * 32);
#pragma unroll
            for (int q = 0; q < 8; ++q) accg[kc][q] += (float)v0[q];
        }
    }

    // finish mean + cvt to fp16 A-fragments
    float sdeg = 1.0f / (float)(dg > 0 ? dg : 1);
    half8v a0[4];
#pragma unroll
    for (int kc = 0; kc < 4; ++kc)
#pragma unroll
        for (int j = 0; j < 8; ++j) a0[kc][j] = (_Float16)(accg[kc][j] * sdeg);

    // identity-operand fragments straight from row-major hb
    half8v a1[4];
#pragma unroll
    for (int kc = 0; kc < 4; ++kc)
        a1[kc] = *(const half8v*)(hb + ((size_t)arow << 7) + kc * 32 + (quad << 3));

    f32x4 acc[8];
#pragma unroll
    for (int nt = 0; nt < 8; ++nt) acc[nt] = (f32x4){0.f, 0.f, 0.f, 0.f};

#pragma unroll
    for (int kc = 0; kc < 4; ++kc) {
        const short* wp0 = Wf0 + ((size_t)kc * 64 + lane) * 8;
        const short* wp1 = Wf1 + ((size_t)kc * 64 + lane) * 8;
#pragma unroll
        for (int nt = 0; nt < 8; ++nt) {
            half8v b0 = *(const half8v*)(wp0 + (size_t)nt * 2048);
            half8v b1 = *(const half8v*)(wp1 + (size_t)nt * 2048);
            acc[nt] = __builtin_amdgcn_mfma_f32_16x16x32_f16(a0[kc], b0, acc[nt], 0, 0, 0);
            acc[nt] = __builtin_amdgcn_mfma_f32_16x16x32_f16(a1[kc], b1, acc[nt], 0, 0, 0);
        }
    }

    // epilogue: C/D layout col = lane&15, row = quad*4 + reg
    float bcol[8];
#pragma unroll
    for (int nt = 0; nt < 8; ++nt) bcol[nt] = bias[nt * 16 + m16];

    if (Wfc) {
        // fused final FC: lane holds cols nt*16+m16; reduce over 16 m16-lanes
        float w0[8], w1[8];
#pragma unroll
        for (int nt = 0; nt < 8; ++nt) {
            float2 wv = *(const float2*)(Wfc + 2 * (nt * 16 + m16));
            w0[nt] = wv.x;
            w1[nt] = wv.y;
        }
        float b0 = bfc[0], b1 = bfc[1];
#pragma unroll
        for (int r = 0; r < 4; ++r) {
            float p0 = 0.f, p1 = 0.f;
#pragma unroll
            for (int nt = 0; nt < 8; ++nt) {
                float v = fmaxf(acc[nt][r] + bcol[nt], 0.f);   // relu (layer2)
                p0 += v * w0[nt];
                p1 += v * w1[nt];
            }
#pragma unroll
            for (int off = 1; off < 16; off <<= 1) {
                p0 += __shfl_xor(p0, off, 64);
                p1 += __shfl_xor(p1, off, 64);
            }
            int row = row_base + quad * 4 + r;
            if (m16 == 0 && row < NN) {
                float2 o;
                o.x = p0 + b0;
                o.y = p1 + b1;
                *(float2*)(fcout + 2 * (size_t)row) = o;
            }
        }
    } else {
#pragma unroll
        for (int r = 0; r < 4; ++r) {
            int row = row_base + quad * 4 + r;
            if (row >= NN) continue;
            unsigned short* opb = outb + ((size_t)row << 7) + m16;
#pragma unroll
            for (int nt = 0; nt < 8; ++nt) {
                float v = acc[nt][r] + bcol[nt];
                if (relu) v = fmaxf(v, 0.f);
                opb[nt * 16] = f16_bits(v);
            }
        }
    }
}

extern "C" void kernel_launch(void* const* d_in, const int* in_sizes, int n_in,
                              void* d_out, int out_size, void* d_ws, size_t ws_size,
                              hipStream_t stream) {
    const float* x   = (const float*)d_in[0];
    const int* edge  = (const int*)d_in[1];
    const float* W1l = (const float*)d_in[2];
    const float* W1r = (const float*)d_in[3];
    const float* b1  = (const float*)d_in[4];
    const float* W2l = (const float*)d_in[5];
    const float* W2r = (const float*)d_in[6];
    const float* b2  = (const float*)d_in[7];
    const float* Wfc = (const float*)d_in[8];
    const float* bfc = (const float*)d_in[9];
    float* out = (float*)d_out;

    const int* src = edge;        // edge_index[0]
    const int* dst = edge + NE;   // edge_index[1]

    char* ws = (char*)d_ws;
    size_t off = 0;
    auto alloc = [&](size_t bytes) -> char* {
        char* p = ws + off;
        off = (off + bytes + 511) & ~(size_t)511;
        return p;
    };
    int* deg              = (int*)alloc((size_t)NN * 4);
    short* wf             = (short*)alloc((size_t)4 * 16384 * 2);
    unsigned short* col   = (unsigned short*)alloc((size_t)NN * DEGCAP * 2);
    unsigned short* xb    = (unsigned short*)alloc((size_t)(NN + 1) * 128 * 2);
    unsigned short* h1b   = (unsigned short*)alloc((size_t)(NN + 1) * 128 * 2);
    (void)ws_size; (void)in_sizes; (void)n_in; (void)out_size;

    hipMemsetAsync(deg, 0, (size_t)NN * 4, stream);
    k1_kernel<<<K1_GRID, 256, 0, stream>>>(x, xb, W1l, W1r, W2l, W2r, wf,
                                           deg, col, src, dst, h1b);
    fused_sage<<<(NN + 63) / 64, 256, 0, stream>>>(xb, col, deg,
                                                   wf, wf + 16384, b1, h1b,
                                                   (const float*)0, (const float*)0,
                                                   (float*)0, 1);
    fused_sage<<<(NN + 63) / 64, 256, 0, stream>>>(h1b, col, deg,
                                                   wf + 2 * 16384, wf + 3 * 16384, b2,
                                                   (unsigned short*)0, Wfc, bfc, out, 0);
}